// Round 11
// baseline (66.429 us; speedup 1.0000x reference)
//
#include <hip/hip_runtime.h>
#include <hip/hip_bf16.h>
#include <math.h>

typedef short short8 __attribute__((ext_vector_type(8)));
typedef float f32x16 __attribute__((ext_vector_type(16)));
typedef float f32x4  __attribute__((ext_vector_type(4)));

#define BB 16
#define CC 256
#define HH 64
#define WW 64
#define HWX 4096
#define DD 4
#define KD 9
#define KK 81
#define NSLOT 10

__device__ __forceinline__ short bf16c(float x) {
    __hip_bfloat16 h = __float2bfloat16(x);
    return *reinterpret_cast<short*>(&h);
}

// fragment-ready LDS layout: BL[c>>3][w][c&7] bf16, 32 KB per buffer.
// swizzle keeps b128 ops conflict-free on both write and read sides.
__device__ __forceinline__ int bl_byte(int c8, int w) {
    int byte = c8 * 1024 + w * 16;
    return byte ^ (((byte >> 10) & 3) << 4);
}

// 8 dwordx4 loads along w: lane covers w=4*(l&15)..+3, c = wvu*32+(l>>4)*8+ch
__device__ __forceinline__ void b_issue(const float* __restrict__ row,
                                        int wvu, int l, f32x4* v4) {
    const float* p = row + (size_t)(wvu * 32 + (l >> 4) * 8) * HWX + 4 * (l & 15);
    #pragma unroll
    for (int ch = 0; ch < 8; ++ch)
        v4[ch] = *(const f32x4*)(p + (size_t)ch * HWX);
}

// pack + 4 swizzled b128 writes + cross-group sumsq reduce -> part[wvu][w]
__device__ __forceinline__ void b_commit(const f32x4* v4, unsigned short* bufp,
                                         float* partp, int wvu, int l) {
    const int c8 = wvu * 4 + (l >> 4);
    float sswi[4];
    #pragma unroll
    for (int wi = 0; wi < 4; ++wi) {
        short8 st;
        float ss = 0.f;
        #pragma unroll
        for (int ch = 0; ch < 8; ++ch) {
            float x = v4[ch][wi];
            ss += x * x;
            st[ch] = bf16c(x);
        }
        *(short8*)((char*)bufp + bl_byte(c8, 4 * (l & 15) + wi)) = st;
        sswi[wi] = ss;
    }
    #pragma unroll
    for (int wi = 0; wi < 4; ++wi) {
        float s = sswi[wi];
        s += __shfl_xor(s, 16, 64);
        s += __shfl_xor(s, 32, 64);
        sswi[wi] = s;
    }
    if ((l >> 4) == 0) {
        f32x4 p4; p4[0] = sswi[0]; p4[1] = sswi[1]; p4[2] = sswi[2]; p4[3] = sswi[3];
        *(f32x4*)&partp[wvu * 64 + 4 * l] = p4;
    }
}

__global__ __launch_bounds__(512) void corr_mfma(
    const float* __restrict__ fA, const float* __restrict__ fB,
    float* __restrict__ out)
{
    __shared__ __attribute__((aligned(16))) unsigned short buf[2][WW * CC]; // 64 KB
    __shared__ float red[2][2][KD][WW + 1];   // [group][parity], padded scatter
    __shared__ float part[2][8 * WW];         // [parity] sumsq partials ([1] aliases A partials)
    __shared__ float invA_ls[2][WW];

    const int bid = blockIdx.x;                       // 512 blocks
    const int swzb = (bid & 7) * 64 + (bid >> 3);     // XCD-bijective (512%8==0)
    const int b = swzb >> 5, jr = swzb & 31;
    const int h0 = 2 * jr;

    const int tid = threadIdx.x;
    const int l = tid & 63;
    const int wvu = __builtin_amdgcn_readfirstlane(tid >> 6);  // wave id -> SGPR
    const int g = wvu >> 2;                // group: row h0+g   (uniform)
    const int q = wvu & 3;                 // quadrant wave     (uniform)
    const int hg = h0 + g;
    const int ti = q >> 1, tj = q & 1;
    const int ml = l & 31, kg = l >> 5;
    const int m = ti * 32 + ml;            // A row (w)
    const int n = tj * 32 + ml;            // B row (w')

    // ---- A prologue: single pass -> raw-bf16 stage (frag layout) + sumsq ----
    const float* Abase = fA + (size_t)b * CC * HWX + hg * WW;
    {
        float ss = 0.f;
        #pragma unroll
        for (int r = 0; r < 8; ++r) {
            const int c = q * 64 + r * 8;              // uniform
            float v[8]; short8 st;
            #pragma unroll
            for (int j = 0; j < 8; ++j) v[j] = Abase[(size_t)(c + j) * HWX + l];
            #pragma unroll
            for (int j = 0; j < 8; ++j) ss += v[j] * v[j];
            #pragma unroll
            for (int j = 0; j < 8; ++j) st[j] = bf16c(v[j]);
            *(short8*)((char*)buf[g] + bl_byte(q * 8 + r, l)) = st;
        }
        part[1][wvu * 64 + l] = ss;
    }
    for (int i = tid; i < 2 * 2 * KD * (WW + 1); i += 512) ((float*)red)[i] = 0.f;
    __syncthreads();
    if (tid < 2 * WW) {      // wave 0 -> group 0 row, wave 1 -> group 1 row
        const int gg = tid >> 6, ll = tid & 63;
        float s = part[1][(gg * 4 + 0) * 64 + ll] + part[1][(gg * 4 + 1) * 64 + ll]
                + part[1][(gg * 4 + 2) * 64 + ll] + part[1][(gg * 4 + 3) * 64 + ll];
        invA_ls[gg][ll] = 1.f / fmaxf(sqrtf(s), 1e-12f);
    }
    short8 afr[16];
    #pragma unroll
    for (int s = 0; s < 16; ++s)
        afr[s] = *(const short8*)((const char*)buf[g] + bl_byte(s * 2 + kg, m));
    __syncthreads();      // hoist reads + invA done before buf[0] is restaged

    // ---- B pipeline: 10 shared row-slots, ONE barrier per slot ----
    const float* fBb = fB + (size_t)b * CC * HWX;
    {   // prologue: stage slot 0 into buf[0]
        const int hb0 = h0 - DD;
        if ((unsigned)hb0 < HH) {
            f32x4 v4[8];
            b_issue(fBb + (size_t)hb0 * WW, wvu, l, v4);
            b_commit(v4, buf[0], part[0], wvu, l);
        }
    }
    __syncthreads();

    for (int r = 0; r < NSLOT; ++r) {
        const int cur = r & 1;
        const int hb = h0 - DD + r;
        const bool vcur = (unsigned)hb < HH;
        const bool vnext = (r + 1 < NSLOT) && ((unsigned)(hb + 1) < HH);
        const int dy = r - g;
        const bool dyv = (dy >= 0 && dy < KD);
        const bool comp = dyv && vcur;

        // 1. issue next-row loads (8 dwordx4; fly under store + MFMA + epilogue)
        f32x4 v4[8];
        if (vnext) b_issue(fBb + (size_t)(hb + 1) * WW, wvu, l, v4);

        // 2. store previous slot's red (parity cur^1); uniform row per store
        if (r >= 1) {
            const int dyp = (r - 1) - g;
            if (dyp >= 0 && dyp < KD) {
                float* ob = out + (((size_t)b * KK + dyp * KD) * HH + hg) * WW;
                ob[(size_t)q * HWX + l] = red[g][cur ^ 1][q][l];
                ob[(size_t)(q + 4) * HWX + l] = red[g][cur ^ 1][q + 4][l];
                if (q == 0) ob[(size_t)8 * HWX + l] = red[g][cur ^ 1][8][l];
            }
        }

        // 3. all 16 MFMA + epilogue arithmetic
        if (comp) {
            f32x16 acc;
            #pragma unroll
            for (int i = 0; i < 16; ++i) acc[i] = 0.f;
            __builtin_amdgcn_s_setprio(1);
            #pragma unroll
            for (int s = 0; s < 16; ++s) {
                short8 bfr = *(const short8*)((const char*)buf[cur] + bl_byte(s * 2 + kg, n));
                acc = __builtin_amdgcn_mfma_f32_32x32x16_bf16(afr[s], bfr, acc, 0, 0, 0);
            }
            __builtin_amdgcn_s_setprio(0);
            float sB = 0.f;
            #pragma unroll
            for (int qq = 0; qq < 8; ++qq) sB += part[cur][qq * 64 + n];
            const float ibn = 1.f / fmaxf(sqrtf(sB), 1e-12f);
            #pragma unroll
            for (int rr = 0; rr < 16; ++rr) {
                // D layout (m74/m101): col = lane&31 (=w'), row = (rr&3)+8*(rr>>2)+4*kg
                const int w = ti * 32 + (rr & 3) + 8 * (rr >> 2) + 4 * kg;
                const int dx = n - w + 4;
                if (dx >= 0 && dx < KD)
                    red[g][cur][dx][w] = acc[rr] * ibn * invA_ls[g][w];
            }
        } else if (dyv) {
            #pragma unroll
            for (int rr = 0; rr < 16; ++rr) {
                const int w = ti * 32 + (rr & 3) + 8 * (rr >> 2) + 4 * kg;
                const int dx = n - w + 4;
                if (dx >= 0 && dx < KD) red[g][cur][dx][w] = 0.f;
            }
        }

        // 4. single late commit of the staged row (one vmcnt point per slot)
        if (vnext)
            b_commit(v4, buf[cur ^ 1], part[cur ^ 1], wvu, l);
        __syncthreads();
    }

    // final store for slot NSLOT-1
    {
        const int dyp = (NSLOT - 1) - g;
        if (dyp >= 0 && dyp < KD) {
            const int par = (NSLOT - 1) & 1;
            float* ob = out + (((size_t)b * KK + dyp * KD) * HH + hg) * WW;
            ob[(size_t)q * HWX + l] = red[g][par][q][l];
            ob[(size_t)(q + 4) * HWX + l] = red[g][par][q + 4][l];
            if (q == 0) ob[(size_t)8 * HWX + l] = red[g][par][8][l];
        }
    }
}

extern "C" void kernel_launch(void* const* d_in, const int* in_sizes, int n_in,
                              void* d_out, int out_size, void* d_ws, size_t ws_size,
                              hipStream_t stream) {
    const float* fA = (const float*)d_in[0];
    const float* fB = (const float*)d_in[1];
    float* outp = (float*)d_out;
    corr_mfma<<<dim3(BB * HH / 2), 512, 0, stream>>>(fA, fB, outp);
}

// Round 12
// 60.064 us; speedup vs baseline: 1.1060x; 1.1060x over previous
//
#include <hip/hip_runtime.h>
#include <hip/hip_bf16.h>
#include <math.h>

typedef short short8 __attribute__((ext_vector_type(8)));
typedef float f32x16 __attribute__((ext_vector_type(16)));

#define BB 16
#define CC 256
#define HH 64
#define WW 64
#define HWX 4096
#define DD 4
#define KD 9
#define KK 81
#define NSLOT 10

// writer-side LDS visibility barrier WITHOUT vmcnt drain (loads/stores in flight)
#define RAW_BAR() do { \
    asm volatile("s_waitcnt lgkmcnt(0)" ::: "memory"); \
    __builtin_amdgcn_s_barrier(); \
} while (0)

__device__ __forceinline__ short bf16c(float x) {
    __hip_bfloat16 h = __float2bfloat16(x);
    return *reinterpret_cast<short*>(&h);
}

// R9-proven 512B-row layout, 5-bit XOR swizzle (measured 0 conflicts)
__device__ __forceinline__ int lds_byte(int w, int c) {
    return (w * 512 + c * 2) ^ ((w & 31) << 4);
}

// 16 strided loads: c = c0..c0+15 at w=l (c0 wave-uniform)
__device__ __forceinline__ void b_issue16(const float* __restrict__ row,
                                          int c0, int l, float* v) {
    #pragma unroll
    for (int j = 0; j < 16; ++j)
        v[j] = row[(size_t)(c0 + j) * HWX + l];
}

// cvt + 2 swizzled ds_write_b128; returns sumsq partial
__device__ __forceinline__ float b_commit16(const float* v, unsigned short* bufp,
                                            int c0, int l) {
    float ss = 0.f;
    #pragma unroll
    for (int j = 0; j < 16; ++j) ss += v[j] * v[j];
    #pragma unroll
    for (int h = 0; h < 2; ++h) {
        short8 st;
        #pragma unroll
        for (int j = 0; j < 8; ++j) st[j] = bf16c(v[h * 8 + j]);
        *(short8*)((char*)bufp + lds_byte(l, c0 + h * 8)) = st;
    }
    return ss;
}

__global__ __launch_bounds__(512) void corr_mfma(
    const float* __restrict__ fA, const float* __restrict__ fB,
    float* __restrict__ out)
{
    __shared__ __attribute__((aligned(16))) unsigned short buf[2][WW * CC]; // 64 KB
    __shared__ float part[2][8 * WW];   // 4 KB ([1] aliases A partials)
    __shared__ float invA_ls[2][WW];    // 0.5 KB            -> total ~68.5 KB

    const int bid = blockIdx.x;                       // 512 blocks
    const int swzb = (bid & 7) * 64 + (bid >> 3);     // XCD-bijective (512%8==0)
    const int b = swzb >> 5, jr = swzb & 31;
    const int h0 = 2 * jr;

    const int tid = threadIdx.x;
    const int l = tid & 63;
    const int wvu = __builtin_amdgcn_readfirstlane(tid >> 6);  // wave id -> SGPR
    const int g = wvu >> 2;                // group: row h0+g   (uniform)
    const int q = wvu & 3;                 // quadrant wave     (uniform)
    const int hg = h0 + g;
    const int ti = q >> 1, tj = q & 1;
    const int ml = l & 31, kg = l >> 5;
    const int m = ti * 32 + ml;            // A row (w)
    const int n = tj * 32 + ml;            // B row (w')

    // ---- A prologue: single pass -> raw-bf16 stage + sumsq ----
    const float* Abase = fA + (size_t)b * CC * HWX + hg * WW;
    {
        float ss = 0.f;
        #pragma unroll
        for (int r = 0; r < 8; ++r) {
            const int c = q * 64 + r * 8;              // uniform
            float v[8]; short8 st;
            #pragma unroll
            for (int j = 0; j < 8; ++j) v[j] = Abase[(size_t)(c + j) * HWX + l];
            #pragma unroll
            for (int j = 0; j < 8; ++j) ss += v[j] * v[j];
            #pragma unroll
            for (int j = 0; j < 8; ++j) st[j] = bf16c(v[j]);
            *(short8*)((char*)buf[g] + lds_byte(l, c)) = st;
        }
        part[1][wvu * 64 + l] = ss;
    }
    __syncthreads();                                   // bar1: A staged
    if (tid < 2 * WW) {
        const int gg = tid >> 6, ll = tid & 63;
        float s = part[1][(gg * 4 + 0) * 64 + ll] + part[1][(gg * 4 + 1) * 64 + ll]
                + part[1][(gg * 4 + 2) * 64 + ll] + part[1][(gg * 4 + 3) * 64 + ll];
        invA_ls[gg][ll] = 1.f / fmaxf(sqrtf(s), 1e-12f);
    }
    short8 afr[16];
    #pragma unroll
    for (int s = 0; s < 16; ++s)
        afr[s] = *(const short8*)((const char*)buf[g] + lds_byte(m, s * 16 + kg * 8));
    __syncthreads();                                   // bar2: invA visible, hoist done
    {   // fold invA[m] into A fragments (output row m gets invA[m])
        const float iam = invA_ls[g][m];
        #pragma unroll
        for (int s = 0; s < 16; ++s) {
            short8 t = afr[s];
            #pragma unroll
            for (int j = 0; j < 8; ++j) {
                union { unsigned u; float f; } uu;
                uu.u = ((unsigned)(unsigned short)t[j]) << 16;
                t[j] = bf16c(uu.f * iam);
            }
            afr[s] = t;
        }
    }
    // slot-0 B staging into buf[0] (hoist reads completed at bar2)
    const float* fBb = fB + (size_t)b * CC * HWX;
    {
        const int hb0 = h0 - DD;
        if ((unsigned)hb0 < HH) {
            const float* row = fBb + (size_t)hb0 * WW;
            float v[16];
            b_issue16(row, wvu * 32, l, v);
            float ss = b_commit16(v, buf[0], wvu * 32, l);
            b_issue16(row, wvu * 32 + 16, l, v);
            ss += b_commit16(v, buf[0], wvu * 32 + 16, l);
            part[0][wvu * 64 + l] = ss;
        }
    }
    __syncthreads();                                   // bar3: slot 0 ready

    // ---- slot loop: 1 raw barrier per slot, direct banded out-stores ----
    for (int r = 0; r < NSLOT; ++r) {
        const int cur = r & 1;
        const int hb = h0 - DD + r;
        const bool vcur = (unsigned)hb < HH;
        const bool vnext = (r + 1 < NSLOT) && ((unsigned)(hb + 1) < HH);
        const int dy = r - g;
        const bool dyv = (dy >= 0 && dy < KD);
        const bool comp = dyv && vcur;
        const float* nrow = fBb + (size_t)(hb + 1) * WW;
        float* ob = out + (((size_t)b * KK + dy * KD) * HH + hg) * WW;

        // 1. issue half0 of next row
        float v[16];
        if (vnext) b_issue16(nrow, wvu * 32, l, v);

        // 2. MFMA octet 1
        f32x16 acc;
        if (comp) {
            #pragma unroll
            for (int i = 0; i < 16; ++i) acc[i] = 0.f;
            __builtin_amdgcn_s_setprio(1);
            #pragma unroll
            for (int s = 0; s < 8; ++s) {
                short8 bfr = *(const short8*)((const char*)buf[cur] + lds_byte(n, s * 16 + kg * 8));
                acc = __builtin_amdgcn_mfma_f32_32x32x16_bf16(afr[s], bfr, acc, 0, 0, 0);
            }
            __builtin_amdgcn_s_setprio(0);
        }

        // 3. commit half0, issue half1
        float ssn = 0.f;
        if (vnext) {
            ssn = b_commit16(v, buf[cur ^ 1], wvu * 32, l);
            b_issue16(nrow, wvu * 32 + 16, l, v);
        }

        // 4. MFMA octet 2 + direct banded store
        if (comp) {
            __builtin_amdgcn_s_setprio(1);
            #pragma unroll
            for (int s = 8; s < 16; ++s) {
                short8 bfr = *(const short8*)((const char*)buf[cur] + lds_byte(n, s * 16 + kg * 8));
                acc = __builtin_amdgcn_mfma_f32_32x32x16_bf16(afr[s], bfr, acc, 0, 0, 0);
            }
            __builtin_amdgcn_s_setprio(0);
            float sB = 0.f;
            #pragma unroll
            for (int qq = 0; qq < 8; ++qq) sB += part[cur][qq * 64 + n];
            const float ibn = 1.f / fmaxf(sqrtf(sB), 1e-12f);
            #pragma unroll
            for (int rr = 0; rr < 16; ++rr) {
                // D layout (m74/m101): col = lane&31 (=w'), row = (rr&3)+8*(rr>>2)+4*kg
                const int w = ti * 32 + (rr & 3) + 8 * (rr >> 2) + 4 * kg;
                const int dx = n - w + 4;
                if (dx >= 0 && dx < KD)
                    ob[(size_t)dx * HWX + w] = acc[rr] * ibn;   // invA folded in afr
            }
            if (q == 3) {      // zero the 20 pad-corner entries of this plane
                int i = -1;
                if (l < 10) i = l;
                else if (l >= 16 && l < 26) i = l - 16;
                if (i >= 0) {
                    const int wz0 = (i < 4) ? 0 : (i < 7) ? 1 : (i < 9) ? 2 : 3;
                    const int dx0 = i - ((wz0 == 0) ? 0 : (wz0 == 1) ? 4 : (wz0 == 2) ? 7 : 9);
                    const int wz = (l < 10) ? wz0 : 63 - wz0;
                    const int dxz = (l < 10) ? dx0 : 8 - dx0;
                    ob[(size_t)dxz * HWX + wz] = 0.f;
                }
            }
        } else if (dyv) {
            // whole dy-plane is zero padding; out is poisoned so must write
            for (int i = q * 64 + l; i < KD * WW; i += 256)
                ob[(size_t)(i >> 6) * HWX + (i & 63)] = 0.f;
        }

        // 5. commit half1, publish sumsq partial
        if (vnext) {
            ssn += b_commit16(v, buf[cur ^ 1], wvu * 32 + 16, l);
            part[cur ^ 1][wvu * 64 + l] = ssn;
        }
        RAW_BAR();
    }
}

extern "C" void kernel_launch(void* const* d_in, const int* in_sizes, int n_in,
                              void* d_out, int out_size, void* d_ws, size_t ws_size,
                              hipStream_t stream) {
    const float* fA = (const float*)d_in[0];
    const float* fB = (const float*)d_in[1];
    float* outp = (float*)d_out;
    corr_mfma<<<dim3(BB * HH / 2), 512, 0, stream>>>(fA, fB, outp);
}